// Round 1
// baseline (740.590 us; speedup 1.0000x reference)
//
#include <hip/hip_runtime.h>

// MultiRelGraphTransformer on MI355X.
// Algebraic restructure: per-edge matmuls commute with scatter-add since W is
// edge-invariant =>  SpMM (gather-sum of H rows by dst) + one [B*N,384]@[384,128]
// GEMM per layer, plus degree-weighted biases and ea-sum @ edge_W.
// CSR built in-kernel each call (counting sort); reused across both layers.

#define NNODES 20000
#define NB     4
#define BROWS  (NB * NNODES)   // 80000
#define DN     64
#define DM     128
#define NE     160000
#define LN_EPS 1e-5f

// ---------- bf16 helpers (manual, RNE) ----------
__device__ inline float bf2f(unsigned short u) {
    union { unsigned int i; float f; } x; x.i = ((unsigned int)u) << 16; return x.f;
}
__device__ inline unsigned short f2bf(float f) {
    union { float f; unsigned int i; } x; x.f = f;
    unsigned int r = x.i + 0x7FFFu + ((x.i >> 16) & 1u);
    return (unsigned short)(r >> 16);
}

// ---------- K1: degree histogram ----------
__global__ void k_hist(const int* __restrict__ ei0, const int* __restrict__ ei1,
                       const int* __restrict__ ei2, int* __restrict__ deg) {
    int tid = blockIdx.x * blockDim.x + threadIdx.x;
    if (tid >= 3 * NE) return;
    int r = tid / NE, e = tid - r * NE;
    const int* ei = (r == 0) ? ei0 : ((r == 1) ? ei1 : ei2);
    int dst = ei[NE + e];
    atomicAdd(&deg[r * NNODES + dst], 1);
}

// ---------- K2: exclusive scan per relation (one block per relation) ----------
__global__ __launch_bounds__(1024) void k_scan(const int* __restrict__ deg,
                                               int* __restrict__ offs,
                                               int* __restrict__ cursor) {
    int r = blockIdx.x;
    int t = threadIdx.x;
    __shared__ int sm[1024];
    __shared__ int s_running;
    if (t == 0) s_running = 0;
    __syncthreads();
    const int nchunks = (NNODES + 1023) / 1024;
    for (int c = 0; c < nchunks; ++c) {
        int i = c * 1024 + t;
        int v = (i < NNODES) ? deg[r * NNODES + i] : 0;
        int orig = v;
        // inclusive Hillis-Steele scan in LDS
        for (int off = 1; off < 1024; off <<= 1) {
            sm[t] = v;
            __syncthreads();
            if (t >= off) v += sm[t - off];
            __syncthreads();
        }
        int excl = v - orig;
        int run = s_running;
        if (i < NNODES) {
            offs[r * (NNODES + 1) + i] = run + excl;
            cursor[r * NNODES + i]     = run + excl;
        }
        __syncthreads();
        if (t == 1023) s_running = run + v;
        __syncthreads();
    }
    if (t == 0) offs[r * (NNODES + 1) + NNODES] = s_running;
}

// ---------- K3: counting-sort scatter (src + edge id per slot) ----------
__global__ void k_scatter(const int* __restrict__ ei0, const int* __restrict__ ei1,
                          const int* __restrict__ ei2, int* __restrict__ cursor,
                          int* __restrict__ srcs, int* __restrict__ eids) {
    int tid = blockIdx.x * blockDim.x + threadIdx.x;
    if (tid >= 3 * NE) return;
    int r = tid / NE, e = tid - r * NE;
    const int* ei = (r == 0) ? ei0 : ((r == 1) ? ei1 : ei2);
    int src = ei[e], dst = ei[NE + e];
    int p = atomicAdd(&cursor[r * NNODES + dst], 1);
    srcs[r * NE + p] = src;
    eids[r * NE + p] = e;
}

// ---------- K4: S[r][n][16] = sum of ea_r over incoming edges ----------
__global__ __launch_bounds__(64) void k_sgather(const int* __restrict__ offs,
                                                const int* __restrict__ eids,
                                                const float* __restrict__ ea0,
                                                const float* __restrict__ ea1,
                                                float* __restrict__ S) {
    int bi = blockIdx.x;                 // 0 .. 2*NNODES-1
    int r = bi / NNODES, n = bi - r * NNODES;
    const float* ea = r ? ea1 : ea0;
    int lane = threadIdx.x;
    int k = lane & 15, sub = lane >> 4;
    int j0 = offs[r * (NNODES + 1) + n], j1 = offs[r * (NNODES + 1) + n + 1];
    float acc = 0.f;
    for (int j = j0 + sub; j < j1; j += 4) {
        int e = eids[r * NE + j];
        acc += ea[e * 16 + k];
    }
    acc += __shfl_xor(acc, 16, 64);
    acc += __shfl_xor(acc, 32, 64);
    if (lane < 16) S[(r * NNODES + n) * 16 + k] = acc;
}

// ---------- K5: input projection H = node_feat @ in_W + in_b ----------
__global__ __launch_bounds__(256) void k_proj(const float* __restrict__ X,
                                              const float* __restrict__ W,
                                              const float* __restrict__ bias,
                                              float* __restrict__ H) {
    __shared__ float Xs[64][68];     // pad 68: staging/compute conflict-free
    __shared__ float Ws[64][128];
    int t = threadIdx.x;
    int m0 = blockIdx.x * 64;
    // stage X tile (64 rows x 64)
#pragma unroll
    for (int i = 0; i < 4; ++i) {
        int lin = t + 256 * i;
        int row = lin >> 4, c4 = lin & 15;
        float4 v = *(const float4*)(X + (size_t)(m0 + row) * DN + c4 * 4);
        *(float4*)&Xs[row][c4 * 4] = v;
    }
    // stage W (64 x 128)
#pragma unroll
    for (int i = 0; i < 8; ++i) {
        int lin = t + 256 * i;
        int row = lin >> 5, c4 = lin & 31;
        *(float4*)&Ws[row][c4 * 4] = *(const float4*)(W + (size_t)row * DM + c4 * 4);
    }
    __syncthreads();
    int tc = t & 31, tr = t >> 5;
    float acc[8][4];
#pragma unroll
    for (int i = 0; i < 8; ++i)
#pragma unroll
        for (int j = 0; j < 4; ++j) acc[i][j] = 0.f;

    for (int kk = 0; kk < 64; kk += 4) {
        float4 w0 = *(float4*)&Ws[kk + 0][tc * 4];
        float4 w1 = *(float4*)&Ws[kk + 1][tc * 4];
        float4 w2 = *(float4*)&Ws[kk + 2][tc * 4];
        float4 w3 = *(float4*)&Ws[kk + 3][tc * 4];
#pragma unroll
        for (int i = 0; i < 8; ++i) {
            float4 g = *(float4*)&Xs[tr * 8 + i][kk];
            acc[i][0] = fmaf(g.x, w0.x, fmaf(g.y, w1.x, fmaf(g.z, w2.x, fmaf(g.w, w3.x, acc[i][0]))));
            acc[i][1] = fmaf(g.x, w0.y, fmaf(g.y, w1.y, fmaf(g.z, w2.y, fmaf(g.w, w3.y, acc[i][1]))));
            acc[i][2] = fmaf(g.x, w0.z, fmaf(g.y, w1.z, fmaf(g.z, w2.z, fmaf(g.w, w3.z, acc[i][2]))));
            acc[i][3] = fmaf(g.x, w0.w, fmaf(g.y, w1.w, fmaf(g.z, w2.w, fmaf(g.w, w3.w, acc[i][3]))));
        }
    }
    float4 b4 = *(const float4*)(bias + tc * 4);
#pragma unroll
    for (int i = 0; i < 8; ++i) {
        int row = m0 + tr * 8 + i;
        float4 o;
        o.x = acc[i][0] + b4.x; o.y = acc[i][1] + b4.y;
        o.z = acc[i][2] + b4.z; o.w = acc[i][3] + b4.w;
        *(float4*)(H + (size_t)row * DM + tc * 4) = o;
    }
}

// ---------- K6: per-layer node bias map SB[n][128] ----------
__global__ __launch_bounds__(128) void k_sb(const int* __restrict__ deg,
                                            const float* __restrict__ S,
                                            const float* __restrict__ node_b,  // [3][128]
                                            const float* __restrict__ edge_W,  // [2][16][128]
                                            const float* __restrict__ edge_b,  // [2][128]
                                            float* __restrict__ SB) {
    int n = blockIdx.x, j = threadIdx.x;
    __shared__ float sS[2][16];
    __shared__ int sdeg[3];
    if (j < 32) sS[j >> 4][j & 15] = S[(((j >> 4)) * NNODES + n) * 16 + (j & 15)];
    if (j >= 32 && j < 35) sdeg[j - 32] = deg[(j - 32) * NNODES + n];
    __syncthreads();
    float val = 0.f;
#pragma unroll
    for (int r = 0; r < 3; ++r) val += (float)sdeg[r] * node_b[r * DM + j];
#pragma unroll
    for (int r = 0; r < 2; ++r) {
        val += (float)sdeg[r] * edge_b[r * DM + j];
#pragma unroll
        for (int k = 0; k < 16; ++k) val += sS[r][k] * edge_W[(r * 16 + k) * DM + j];
    }
    SB[n * DM + j] = val;
}

// ---------- K7: SpMM  G[b*N+n][r*128+c] = sum_{e: dst=n} H[b][src(e)][c] ----------
__global__ __launch_bounds__(256) void k_spmm(const float* __restrict__ H,
                                              const int* __restrict__ offs,
                                              const int* __restrict__ srcs,
                                              unsigned short* __restrict__ G) {
    int n = blockIdx.x;
    int b = threadIdx.x >> 6, lane = threadIdx.x & 63;
    int col = lane * 2;
    const float* Hb = H + (size_t)b * NNODES * DM;
    size_t rowbase = ((size_t)(b * NNODES + n)) * 384;
#pragma unroll
    for (int r = 0; r < 3; ++r) {
        int j0 = offs[r * (NNODES + 1) + n], j1 = offs[r * (NNODES + 1) + n + 1];
        float a0 = 0.f, a1 = 0.f;
        for (int j = j0; j < j1; ++j) {
            int s = srcs[r * NE + j];
            float2 v = *(const float2*)(Hb + (size_t)s * DM + col);
            a0 += v.x; a1 += v.y;
        }
        ushort2 hv; hv.x = f2bf(a0); hv.y = f2bf(a1);
        *(ushort2*)(G + rowbase + r * 128 + col) = hv;
    }
}

// ---------- K8: fused GEMM (K=384) + bias + residual + ReLU + LayerNorm ----------
__global__ __launch_bounds__(256) void k_gemm_ln(const unsigned short* __restrict__ G,  // [BROWS][384] bf16
                                                 const float* __restrict__ W,           // [384][128]
                                                 const float* __restrict__ SB,          // [NNODES][128]
                                                 const float* __restrict__ H,           // [BROWS][128]
                                                 const float* __restrict__ lng,
                                                 const float* __restrict__ lnb,
                                                 float* __restrict__ out) {
    __shared__ float Gs[64][68];
    __shared__ float Ws[64][128];
    int t = threadIdx.x;
    int m0 = blockIdx.x * 64;
    int tc = t & 31, tr = t >> 5;
    float acc[8][4];
#pragma unroll
    for (int i = 0; i < 8; ++i)
#pragma unroll
        for (int j = 0; j < 4; ++j) acc[i][j] = 0.f;

    for (int kc = 0; kc < 6; ++kc) {
        // stage G chunk (64 rows x 64 bf16 -> fp32 LDS)
#pragma unroll
        for (int i = 0; i < 4; ++i) {
            int lin = t + 256 * i;
            int row = lin >> 4, c4 = lin & 15;
            ushort4 v = *(const ushort4*)(G + (size_t)(m0 + row) * 384 + kc * 64 + c4 * 4);
            float4 f; f.x = bf2f(v.x); f.y = bf2f(v.y); f.z = bf2f(v.z); f.w = bf2f(v.w);
            *(float4*)&Gs[row][c4 * 4] = f;
        }
        // stage W chunk (64 x 128)
#pragma unroll
        for (int i = 0; i < 8; ++i) {
            int lin = t + 256 * i;
            int row = lin >> 5, c4 = lin & 31;
            *(float4*)&Ws[row][c4 * 4] = *(const float4*)(W + (size_t)(kc * 64 + row) * DM + c4 * 4);
        }
        __syncthreads();
        for (int kk = 0; kk < 64; kk += 4) {
            float4 w0 = *(float4*)&Ws[kk + 0][tc * 4];
            float4 w1 = *(float4*)&Ws[kk + 1][tc * 4];
            float4 w2 = *(float4*)&Ws[kk + 2][tc * 4];
            float4 w3 = *(float4*)&Ws[kk + 3][tc * 4];
#pragma unroll
            for (int i = 0; i < 8; ++i) {
                float4 g = *(float4*)&Gs[tr * 8 + i][kk];
                acc[i][0] = fmaf(g.x, w0.x, fmaf(g.y, w1.x, fmaf(g.z, w2.x, fmaf(g.w, w3.x, acc[i][0]))));
                acc[i][1] = fmaf(g.x, w0.y, fmaf(g.y, w1.y, fmaf(g.z, w2.y, fmaf(g.w, w3.y, acc[i][1]))));
                acc[i][2] = fmaf(g.x, w0.z, fmaf(g.y, w1.z, fmaf(g.z, w2.z, fmaf(g.w, w3.z, acc[i][2]))));
                acc[i][3] = fmaf(g.x, w0.w, fmaf(g.y, w1.w, fmaf(g.z, w2.w, fmaf(g.w, w3.w, acc[i][3]))));
            }
        }
        __syncthreads();
    }

    // epilogue: agg = acc + SB[n]; x = H + relu(agg); LayerNorm over 128 cols
    float4 g4 = *(const float4*)(lng + tc * 4);
    float4 b4 = *(const float4*)(lnb + tc * 4);
#pragma unroll
    for (int i = 0; i < 8; ++i) {
        int row = m0 + tr * 8 + i;
        int n = row % NNODES;
        float4 h  = *(const float4*)(H  + (size_t)row * DM + tc * 4);
        float4 sb = *(const float4*)(SB + (size_t)n  * DM + tc * 4);
        float x0 = h.x + fmaxf(acc[i][0] + sb.x, 0.f);
        float x1 = h.y + fmaxf(acc[i][1] + sb.y, 0.f);
        float x2 = h.z + fmaxf(acc[i][2] + sb.z, 0.f);
        float x3 = h.w + fmaxf(acc[i][3] + sb.w, 0.f);
        float s1 = x0 + x1 + x2 + x3;
        float s2 = x0 * x0 + x1 * x1 + x2 * x2 + x3 * x3;
#pragma unroll
        for (int m = 1; m <= 16; m <<= 1) {
            s1 += __shfl_xor(s1, m, 64);
            s2 += __shfl_xor(s2, m, 64);
        }
        float mu  = s1 * (1.f / 128.f);
        float var = s2 * (1.f / 128.f) - mu * mu;
        float inv = rsqrtf(var + LN_EPS);
        float4 o;
        o.x = (x0 - mu) * inv * g4.x + b4.x;
        o.y = (x1 - mu) * inv * g4.y + b4.y;
        o.z = (x2 - mu) * inv * g4.z + b4.z;
        o.w = (x3 - mu) * inv * g4.w + b4.w;
        *(float4*)(out + (size_t)row * DM + tc * 4) = o;
    }
}

extern "C" void kernel_launch(void* const* d_in, const int* in_sizes, int n_in,
                              void* d_out, int out_size, void* d_ws, size_t ws_size,
                              hipStream_t stream) {
    const float* node_feat = (const float*)d_in[0];
    const float* in_W   = (const float*)d_in[1];
    const float* in_b   = (const float*)d_in[2];
    const float* node_W = (const float*)d_in[3];   // [2][3][128][128]
    const float* node_b = (const float*)d_in[4];   // [2][3][128]
    const float* edge_W = (const float*)d_in[5];   // [2][2][16][128]
    const float* edge_b = (const float*)d_in[6];   // [2][2][128]
    const float* ln_g   = (const float*)d_in[7];   // [2][128]
    const float* ln_b   = (const float*)d_in[8];   // [2][128]
    const float* ea0    = (const float*)d_in[9];
    const float* ea1    = (const float*)d_in[10];
    const int*   ei0    = (const int*)d_in[11];
    const int*   ei1    = (const int*)d_in[12];
    const int*   ei2    = (const int*)d_in[13];
    float* out = (float*)d_out;

    char* ws = (char*)d_ws;
    size_t off = 0;
    auto alloc = [&](size_t bytes) -> void* {
        void* p = ws + off;
        off = (off + bytes + 255) & ~(size_t)255;
        return p;
    };
    float*          H      = (float*)alloc((size_t)BROWS * DM * 4);        // 41 MB
    unsigned short* G      = (unsigned short*)alloc((size_t)BROWS * 384 * 2); // 61 MB
    float*          SB     = (float*)alloc((size_t)NNODES * DM * 4);       // 10 MB
    float*          S      = (float*)alloc((size_t)2 * NNODES * 16 * 4);
    int*            deg    = (int*)alloc((size_t)3 * NNODES * 4);
    int*            offs   = (int*)alloc((size_t)3 * (NNODES + 1) * 4);
    int*            cursor = (int*)alloc((size_t)3 * NNODES * 4);
    int*            srcs   = (int*)alloc((size_t)3 * NE * 4);
    int*            eids   = (int*)alloc((size_t)3 * NE * 4);

    hipMemsetAsync(deg, 0, (size_t)3 * NNODES * 4, stream);

    k_hist<<<(3 * NE + 255) / 256, 256, 0, stream>>>(ei0, ei1, ei2, deg);
    k_scan<<<3, 1024, 0, stream>>>(deg, offs, cursor);
    k_scatter<<<(3 * NE + 255) / 256, 256, 0, stream>>>(ei0, ei1, ei2, cursor, srcs, eids);
    k_sgather<<<2 * NNODES, 64, 0, stream>>>(offs, eids, ea0, ea1, S);
    k_proj<<<BROWS / 64, 256, 0, stream>>>(node_feat, in_W, in_b, H);

    for (int l = 0; l < 2; ++l) {
        k_sb<<<NNODES, 128, 0, stream>>>(deg, S,
                                         node_b + (size_t)l * 3 * DM,
                                         edge_W + (size_t)l * 2 * 16 * DM,
                                         edge_b + (size_t)l * 2 * DM,
                                         SB);
        k_spmm<<<NNODES, 256, 0, stream>>>(H, offs, srcs, G);
        float* o = (l == 1) ? out : H;
        k_gemm_ln<<<BROWS / 64, 256, 0, stream>>>(G, node_W + (size_t)l * 3 * DM * DM, SB, H,
                                                  ln_g + (size_t)l * DM, ln_b + (size_t)l * DM, o);
    }
}

// Round 2
// 477.031 us; speedup vs baseline: 1.5525x; 1.5525x over previous
//
#include <hip/hip_runtime.h>

// MultiRelGraphTransformer on MI355X — round 2.
// SpMM (gather-sum by dst) + bf16 MFMA GEMM per layer.
// Changes vs r1: (a) bucketed counting (no scan kernel), (b) XCD-batch
// affinity in SpMM, (c) k_gemm_ln rewritten with mfma_f32_16x16x32_bf16.

#define NNODES 20000
#define NB     4
#define BROWS  (NB * NNODES)   // 80000
#define DN     64
#define DM     128
#define NE     160000
#define CAP    64              // bucket capacity per (relation,dst); Poisson(8) max ~30
#define LN_EPS 1e-5f

typedef __attribute__((ext_vector_type(8))) short bf16x8;
typedef __attribute__((ext_vector_type(4))) float f32x4;

// ---------- bf16 helpers (manual, RNE) ----------
__device__ inline float bf2f(unsigned short u) {
    union { unsigned int i; float f; } x; x.i = ((unsigned int)u) << 16; return x.f;
}
__device__ inline unsigned short f2bf(float f) {
    union { float f; unsigned int i; } x; x.f = f;
    unsigned int r = x.i + 0x7FFFu + ((x.i >> 16) & 1u);
    return (unsigned short)(r >> 16);
}

// ---------- K1: counting-sort into fixed buckets (cursor doubles as deg) ----------
__global__ void k_scatter(const int* __restrict__ ei0, const int* __restrict__ ei1,
                          const int* __restrict__ ei2, int* __restrict__ cursor,
                          int* __restrict__ srcs, int* __restrict__ eids) {
    int tid = blockIdx.x * blockDim.x + threadIdx.x;
    if (tid >= 3 * NE) return;
    int r = tid / NE, e = tid - r * NE;
    const int* ei = (r == 0) ? ei0 : ((r == 1) ? ei1 : ei2);
    int src = ei[e], dst = ei[NE + e];
    int p = atomicAdd(&cursor[r * NNODES + dst], 1);
    if (p < CAP) {
        srcs[(r * NNODES + dst) * CAP + p] = src;
        eids[(r * NNODES + dst) * CAP + p] = e;
    }
}

// ---------- K2: S[r][n][16] = sum of ea_r over incoming edges ----------
__global__ __launch_bounds__(64) void k_sgather(const int* __restrict__ deg,
                                                const int* __restrict__ eids,
                                                const float* __restrict__ ea0,
                                                const float* __restrict__ ea1,
                                                float* __restrict__ S) {
    int bi = blockIdx.x;                 // 0 .. 2*NNODES-1
    int r = bi / NNODES, n = bi - r * NNODES;
    const float* ea = r ? ea1 : ea0;
    int lane = threadIdx.x;
    int k = lane & 15, sub = lane >> 4;
    int dg = deg[r * NNODES + n];
    const int* bk = eids + (size_t)(r * NNODES + n) * CAP;
    float acc = 0.f;
    for (int j = sub; j < dg; j += 4) {
        int e = bk[j];
        acc += ea[e * 16 + k];
    }
    acc += __shfl_xor(acc, 16, 64);
    acc += __shfl_xor(acc, 32, 64);
    if (lane < 16) S[(r * NNODES + n) * 16 + k] = acc;
}

// ---------- K3: transpose node_W -> Wt[l][n][k] bf16 (k = r*128+kk, K=384) ----------
__global__ __launch_bounds__(256) void k_wprep(const float* __restrict__ W,
                                               unsigned short* __restrict__ Wt) {
    int lin = blockIdx.x * 256 + threadIdx.x;   // 2*3*128*128 = 98304
    int n = lin & 127;
    int rest = lin >> 7;          // [0, 768)
    int kk = rest & 127;
    int lr = rest >> 7;           // [0, 6)
    int r = lr % 3, l = lr / 3;
    float v = W[(((size_t)(l * 3 + r) * 128) + kk) * 128 + n];
    Wt[((size_t)(l * 128 + n)) * 384 + r * 128 + kk] = f2bf(v);
}

// ---------- K4: input projection H = node_feat @ in_W + in_b (fp32 vector) ----------
__global__ __launch_bounds__(256) void k_proj(const float* __restrict__ X,
                                              const float* __restrict__ W,
                                              const float* __restrict__ bias,
                                              float* __restrict__ H) {
    __shared__ float Xs[64][68];
    __shared__ float Ws[64][128];
    int t = threadIdx.x;
    int m0 = blockIdx.x * 64;
#pragma unroll
    for (int i = 0; i < 4; ++i) {
        int lin = t + 256 * i;
        int row = lin >> 4, c4 = lin & 15;
        float4 v = *(const float4*)(X + (size_t)(m0 + row) * DN + c4 * 4);
        *(float4*)&Xs[row][c4 * 4] = v;
    }
#pragma unroll
    for (int i = 0; i < 8; ++i) {
        int lin = t + 256 * i;
        int row = lin >> 5, c4 = lin & 31;
        *(float4*)&Ws[row][c4 * 4] = *(const float4*)(W + (size_t)row * DM + c4 * 4);
    }
    __syncthreads();
    int tc = t & 31, tr = t >> 5;
    float acc[8][4];
#pragma unroll
    for (int i = 0; i < 8; ++i)
#pragma unroll
        for (int j = 0; j < 4; ++j) acc[i][j] = 0.f;

    for (int kk = 0; kk < 64; kk += 4) {
        float4 w0 = *(float4*)&Ws[kk + 0][tc * 4];
        float4 w1 = *(float4*)&Ws[kk + 1][tc * 4];
        float4 w2 = *(float4*)&Ws[kk + 2][tc * 4];
        float4 w3 = *(float4*)&Ws[kk + 3][tc * 4];
#pragma unroll
        for (int i = 0; i < 8; ++i) {
            float4 g = *(float4*)&Xs[tr * 8 + i][kk];
            acc[i][0] = fmaf(g.x, w0.x, fmaf(g.y, w1.x, fmaf(g.z, w2.x, fmaf(g.w, w3.x, acc[i][0]))));
            acc[i][1] = fmaf(g.x, w0.y, fmaf(g.y, w1.y, fmaf(g.z, w2.y, fmaf(g.w, w3.y, acc[i][1]))));
            acc[i][2] = fmaf(g.x, w0.z, fmaf(g.y, w1.z, fmaf(g.z, w2.z, fmaf(g.w, w3.z, acc[i][2]))));
            acc[i][3] = fmaf(g.x, w0.w, fmaf(g.y, w1.w, fmaf(g.z, w2.w, fmaf(g.w, w3.w, acc[i][3]))));
        }
    }
    float4 b4 = *(const float4*)(bias + tc * 4);
#pragma unroll
    for (int i = 0; i < 8; ++i) {
        int row = m0 + tr * 8 + i;
        float4 o;
        o.x = acc[i][0] + b4.x; o.y = acc[i][1] + b4.y;
        o.z = acc[i][2] + b4.z; o.w = acc[i][3] + b4.w;
        *(float4*)(H + (size_t)row * DM + tc * 4) = o;
    }
}

// ---------- K5: per-layer node bias map SB[n][128] ----------
__global__ __launch_bounds__(128) void k_sb(const int* __restrict__ deg,
                                            const float* __restrict__ S,
                                            const float* __restrict__ node_b,  // [3][128]
                                            const float* __restrict__ edge_W,  // [2][16][128]
                                            const float* __restrict__ edge_b,  // [2][128]
                                            float* __restrict__ SB) {
    int n = blockIdx.x, j = threadIdx.x;
    __shared__ float sS[2][16];
    __shared__ int sdeg[3];
    if (j < 32) sS[j >> 4][j & 15] = S[(((j >> 4)) * NNODES + n) * 16 + (j & 15)];
    if (j >= 32 && j < 35) sdeg[j - 32] = deg[(j - 32) * NNODES + n];
    __syncthreads();
    float val = 0.f;
#pragma unroll
    for (int r = 0; r < 3; ++r) val += (float)sdeg[r] * node_b[r * DM + j];
#pragma unroll
    for (int r = 0; r < 2; ++r) {
        val += (float)sdeg[r] * edge_b[r * DM + j];
#pragma unroll
        for (int k = 0; k < 16; ++k) val += sS[r][k] * edge_W[(r * 16 + k) * DM + j];
    }
    SB[n * DM + j] = val;
}

// ---------- K6: SpMM  G[b*N+n][r*128+c] = sum_{e: dst=n} H[b][src(e)][c] ----------
// XCD affinity: b fixed per block via blockIdx&7 -> each XCD's L2 sees one batch.
__global__ __launch_bounds__(256) void k_spmm(const float* __restrict__ H,
                                              const int* __restrict__ deg,
                                              const int* __restrict__ srcs,
                                              unsigned short* __restrict__ G) {
    int blk = blockIdx.x;                 // 10000 blocks
    int b = (blk >> 1) & 3;               // xcd = blk&7 -> batch = xcd>>1
    int idx = ((blk >> 3) << 1) + (blk & 1);   // [0, 2500)
    int n0 = idx * 8;
    int g = threadIdx.x >> 5, lane32 = threadIdx.x & 31;
    int n = n0 + g;
    int c4 = lane32 * 4;
    const float* Hb = H + (size_t)b * NNODES * DM;
    size_t rowbase = ((size_t)(b * NNODES + n)) * 384;
#pragma unroll
    for (int r = 0; r < 3; ++r) {
        int dg = deg[r * NNODES + n];
        const int* bk = srcs + (size_t)(r * NNODES + n) * CAP;
        float4 a = {0.f, 0.f, 0.f, 0.f};
        int j = 0;
        for (; j + 1 < dg; j += 2) {
            int s0 = bk[j], s1 = bk[j + 1];
            float4 v0 = *(const float4*)(Hb + (size_t)s0 * DM + c4);
            float4 v1 = *(const float4*)(Hb + (size_t)s1 * DM + c4);
            a.x += v0.x + v1.x; a.y += v0.y + v1.y;
            a.z += v0.z + v1.z; a.w += v0.w + v1.w;
        }
        if (j < dg) {
            int s0 = bk[j];
            float4 v0 = *(const float4*)(Hb + (size_t)s0 * DM + c4);
            a.x += v0.x; a.y += v0.y; a.z += v0.z; a.w += v0.w;
        }
        ushort4 hv;
        hv.x = f2bf(a.x); hv.y = f2bf(a.y); hv.z = f2bf(a.z); hv.w = f2bf(a.w);
        *(ushort4*)(G + rowbase + r * 128 + c4) = hv;
    }
}

// ---------- K7: bf16 MFMA GEMM [64x384]@[384x128] + bias + residual + ReLU + LN ----------
// A-frag: A[m=lane&15][k=(lane>>4)*8+j]; C/D: col=lane&15, row=(lane>>4)*4+reg.
__global__ __launch_bounds__(256) void k_gemm_ln(const unsigned short* __restrict__ G,   // [BROWS][384] bf16
                                                 const unsigned short* __restrict__ Wt,  // [128 n][384 k] bf16
                                                 const float* __restrict__ SB,
                                                 const float* H,
                                                 const float* __restrict__ lng,
                                                 const float* __restrict__ lnb,
                                                 float* out) {
    __shared__ __align__(16) unsigned short Gs[64][104];    // 96 k per chunk, pad->104
    __shared__ __align__(16) unsigned short Ws[128][104];
    int t = threadIdx.x;
    int m0 = blockIdx.x * 64;
    int w = t >> 6, lane = t & 63;
    int q = lane >> 4, lm = lane & 15;

    f32x4 acc[8];
#pragma unroll
    for (int ct = 0; ct < 8; ++ct) acc[ct] = (f32x4){0.f, 0.f, 0.f, 0.f};

    for (int kc = 0; kc < 4; ++kc) {
        // stage G chunk: 64 rows x 96 k
#pragma unroll
        for (int i = 0; i < 3; ++i) {
            int lin = t + 256 * i;             // 0..767
            int row = lin / 12, seg = lin % 12;
            *(uint4*)&Gs[row][seg * 8] =
                *(const uint4*)(G + (size_t)(m0 + row) * 384 + kc * 96 + seg * 8);
        }
        // stage Wt chunk: 128 n x 96 k
#pragma unroll
        for (int i = 0; i < 6; ++i) {
            int lin = t + 256 * i;             // 0..1535
            int row = lin / 12, seg = lin % 12;
            *(uint4*)&Ws[row][seg * 8] =
                *(const uint4*)(Wt + (size_t)row * 384 + kc * 96 + seg * 8);
        }
        __syncthreads();
#pragma unroll
        for (int kt = 0; kt < 3; ++kt) {
            bf16x8 a = *(const bf16x8*)&Gs[w * 16 + lm][kt * 32 + q * 8];
#pragma unroll
            for (int ct = 0; ct < 8; ++ct) {
                bf16x8 bf = *(const bf16x8*)&Ws[ct * 16 + lm][kt * 32 + q * 8];
                acc[ct] = __builtin_amdgcn_mfma_f32_16x16x32_bf16(a, bf, acc[ct], 0, 0, 0);
            }
        }
        __syncthreads();
    }

    // epilogue: x = H + relu(acc + SB); LayerNorm over 128 cols; out
    float gc[8], bc[8];
#pragma unroll
    for (int ct = 0; ct < 8; ++ct) {
        int col = ct * 16 + lm;
        gc[ct] = lng[col]; bc[ct] = lnb[col];
    }
#pragma unroll
    for (int reg = 0; reg < 4; ++reg) {
        int row = m0 + w * 16 + q * 4 + reg;
        int n = row % NNODES;
        float xv[8];
        float s1 = 0.f, s2 = 0.f;
#pragma unroll
        for (int ct = 0; ct < 8; ++ct) {
            int col = ct * 16 + lm;
            float h  = H[(size_t)row * DM + col];
            float sb = SB[(size_t)n * DM + col];
            float v = h + fmaxf(acc[ct][reg] + sb, 0.f);
            xv[ct] = v; s1 += v; s2 += v * v;
        }
#pragma unroll
        for (int m = 1; m <= 8; m <<= 1) {
            s1 += __shfl_xor(s1, m, 64);
            s2 += __shfl_xor(s2, m, 64);
        }
        float mu  = s1 * (1.f / 128.f);
        float var = s2 * (1.f / 128.f) - mu * mu;
        float inv = rsqrtf(var + LN_EPS);
#pragma unroll
        for (int ct = 0; ct < 8; ++ct) {
            int col = ct * 16 + lm;
            out[(size_t)row * DM + col] = (xv[ct] - mu) * inv * gc[ct] + bc[ct];
        }
    }
}

extern "C" void kernel_launch(void* const* d_in, const int* in_sizes, int n_in,
                              void* d_out, int out_size, void* d_ws, size_t ws_size,
                              hipStream_t stream) {
    const float* node_feat = (const float*)d_in[0];
    const float* in_W   = (const float*)d_in[1];
    const float* in_b   = (const float*)d_in[2];
    const float* node_W = (const float*)d_in[3];   // [2][3][128][128]
    const float* node_b = (const float*)d_in[4];   // [2][3][128]
    const float* edge_W = (const float*)d_in[5];   // [2][2][16][128]
    const float* edge_b = (const float*)d_in[6];   // [2][2][128]
    const float* ln_g   = (const float*)d_in[7];   // [2][128]
    const float* ln_b   = (const float*)d_in[8];   // [2][128]
    const float* ea0    = (const float*)d_in[9];
    const float* ea1    = (const float*)d_in[10];
    const int*   ei0    = (const int*)d_in[11];
    const int*   ei1    = (const int*)d_in[12];
    const int*   ei2    = (const int*)d_in[13];
    float* out = (float*)d_out;

    char* ws = (char*)d_ws;
    size_t off = 0;
    auto alloc = [&](size_t bytes) -> void* {
        void* p = ws + off;
        off = (off + bytes + 255) & ~(size_t)255;
        return p;
    };
    float*          H      = (float*)alloc((size_t)BROWS * DM * 4);            // 41 MB
    unsigned short* G      = (unsigned short*)alloc((size_t)BROWS * 384 * 2);  // 61 MB
    float*          SB     = (float*)alloc((size_t)NNODES * DM * 4);           // 10 MB
    float*          S      = (float*)alloc((size_t)2 * NNODES * 16 * 4);
    int*            cursor = (int*)alloc((size_t)3 * NNODES * 4);              // doubles as deg
    int*            srcs   = (int*)alloc((size_t)3 * NNODES * CAP * 4);        // 15 MB
    int*            eids   = (int*)alloc((size_t)3 * NNODES * CAP * 4);        // 15 MB
    unsigned short* Wt     = (unsigned short*)alloc((size_t)2 * 128 * 384 * 2);

    hipMemsetAsync(cursor, 0, (size_t)3 * NNODES * 4, stream);

    k_scatter<<<(3 * NE + 255) / 256, 256, 0, stream>>>(ei0, ei1, ei2, cursor, srcs, eids);
    k_sgather<<<2 * NNODES, 64, 0, stream>>>(cursor, eids, ea0, ea1, S);
    k_wprep<<<384, 256, 0, stream>>>(node_W, Wt);
    k_proj<<<BROWS / 64, 256, 0, stream>>>(node_feat, in_W, in_b, H);

    for (int l = 0; l < 2; ++l) {
        k_sb<<<NNODES, 128, 0, stream>>>(cursor, S,
                                         node_b + (size_t)l * 3 * DM,
                                         edge_W + (size_t)l * 2 * 16 * DM,
                                         edge_b + (size_t)l * 2 * DM,
                                         SB);
        k_spmm<<<10000, 256, 0, stream>>>(H, cursor, srcs, G);
        float* o = (l == 1) ? out : H;
        k_gemm_ln<<<BROWS / 64, 256, 0, stream>>>(G, Wt + (size_t)l * 128 * 384, SB, H,
                                                  ln_g + (size_t)l * DM, ln_b + (size_t)l * DM, o);
    }
}

// Round 3
// 432.137 us; speedup vs baseline: 1.7138x; 1.1039x over previous
//
#include <hip/hip_runtime.h>

// MultiRelGraphTransformer on MI355X — round 3.
// Changes vs r2: (a) H kept ONLY as bf16 (HB, 20 MB) -> spmm gather bytes
// halve and per-XCD working set ~fits L2; gemm_ln updates HB in place,
// (b) ea-sum S built by coalesced atomicAdd pass (eids buffer deleted),
// (c) both layers' SB in one launch.

#define NNODES 20000
#define NB     4
#define BROWS  (NB * NNODES)   // 80000
#define DN     64
#define DM     128
#define NE     160000
#define CAP    64              // bucket capacity per (relation,dst); Poisson(8)
#define LN_EPS 1e-5f

typedef __attribute__((ext_vector_type(8))) short bf16x8;
typedef __attribute__((ext_vector_type(4))) float f32x4;

__device__ inline float bf2f(unsigned short u) {
    union { unsigned int i; float f; } x; x.i = ((unsigned int)u) << 16; return x.f;
}
__device__ inline unsigned short f2bf(float f) {
    union { float f; unsigned int i; } x; x.f = f;
    unsigned int r = x.i + 0x7FFFu + ((x.i >> 16) & 1u);
    return (unsigned short)(r >> 16);
}

// ---------- K1: counting-sort into fixed buckets (cursor doubles as deg) ----------
__global__ void k_scatter(const int* __restrict__ ei0, const int* __restrict__ ei1,
                          const int* __restrict__ ei2, int* __restrict__ cursor,
                          int* __restrict__ srcs) {
    int tid = blockIdx.x * blockDim.x + threadIdx.x;
    if (tid >= 3 * NE) return;
    int r = tid / NE, e = tid - r * NE;
    const int* ei = (r == 0) ? ei0 : ((r == 1) ? ei1 : ei2);
    int src = ei[e], dst = ei[NE + e];
    int p = atomicAdd(&cursor[r * NNODES + dst], 1);
    if (p < CAP) srcs[(r * NNODES + dst) * CAP + p] = src;
}

// ---------- K2: S[r][dst][16] += ea_r[e]  (coalesced pass, low-contention atomics) ----------
__global__ void k_ea(const int* __restrict__ ei0, const int* __restrict__ ei1,
                     const float* __restrict__ ea0, const float* __restrict__ ea1,
                     float* __restrict__ S) {
    int tid = blockIdx.x * blockDim.x + threadIdx.x;   // 2*NE*4 items, 4 cols each
    if (tid >= 2 * NE * 4) return;
    int c4 = (tid & 3) * 4;
    int er = tid >> 2;
    int r = er / NE, e = er - r * NE;
    const float* ea = r ? ea1 : ea0;
    const int*   ei = r ? ei1 : ei0;
    int dst = ei[NE + e];
    float4 v = *(const float4*)(ea + (size_t)e * 16 + c4);
    float* sp = S + ((size_t)(r * NNODES + dst)) * 16 + c4;
    atomicAdd(sp + 0, v.x); atomicAdd(sp + 1, v.y);
    atomicAdd(sp + 2, v.z); atomicAdd(sp + 3, v.w);
}

// ---------- K3: transpose node_W -> Wt[l][n][k] bf16 (K=384) ----------
__global__ __launch_bounds__(256) void k_wprep(const float* __restrict__ W,
                                               unsigned short* __restrict__ Wt) {
    int lin = blockIdx.x * 256 + threadIdx.x;   // 2*3*128*128 = 98304
    int n = lin & 127;
    int rest = lin >> 7;
    int kk = rest & 127;
    int lr = rest >> 7;
    int r = lr % 3, l = lr / 3;
    float v = W[(((size_t)(l * 3 + r) * 128) + kk) * 128 + n];
    Wt[((size_t)(l * 128 + n)) * 384 + r * 128 + kk] = f2bf(v);
}

// ---------- K4: input projection HB = bf16(node_feat @ in_W + in_b) ----------
__global__ __launch_bounds__(256) void k_proj(const float* __restrict__ X,
                                              const float* __restrict__ W,
                                              const float* __restrict__ bias,
                                              unsigned short* __restrict__ HB) {
    __shared__ float Xs[64][68];
    __shared__ float Ws[64][128];
    int t = threadIdx.x;
    int m0 = blockIdx.x * 64;
#pragma unroll
    for (int i = 0; i < 4; ++i) {
        int lin = t + 256 * i;
        int row = lin >> 4, c4 = lin & 15;
        float4 v = *(const float4*)(X + (size_t)(m0 + row) * DN + c4 * 4);
        *(float4*)&Xs[row][c4 * 4] = v;
    }
#pragma unroll
    for (int i = 0; i < 8; ++i) {
        int lin = t + 256 * i;
        int row = lin >> 5, c4 = lin & 31;
        *(float4*)&Ws[row][c4 * 4] = *(const float4*)(W + (size_t)row * DM + c4 * 4);
    }
    __syncthreads();
    int tc = t & 31, tr = t >> 5;
    float acc[8][4];
#pragma unroll
    for (int i = 0; i < 8; ++i)
#pragma unroll
        for (int j = 0; j < 4; ++j) acc[i][j] = 0.f;

    for (int kk = 0; kk < 64; kk += 4) {
        float4 w0 = *(float4*)&Ws[kk + 0][tc * 4];
        float4 w1 = *(float4*)&Ws[kk + 1][tc * 4];
        float4 w2 = *(float4*)&Ws[kk + 2][tc * 4];
        float4 w3 = *(float4*)&Ws[kk + 3][tc * 4];
#pragma unroll
        for (int i = 0; i < 8; ++i) {
            float4 g = *(float4*)&Xs[tr * 8 + i][kk];
            acc[i][0] = fmaf(g.x, w0.x, fmaf(g.y, w1.x, fmaf(g.z, w2.x, fmaf(g.w, w3.x, acc[i][0]))));
            acc[i][1] = fmaf(g.x, w0.y, fmaf(g.y, w1.y, fmaf(g.z, w2.y, fmaf(g.w, w3.y, acc[i][1]))));
            acc[i][2] = fmaf(g.x, w0.z, fmaf(g.y, w1.z, fmaf(g.z, w2.z, fmaf(g.w, w3.z, acc[i][2]))));
            acc[i][3] = fmaf(g.x, w0.w, fmaf(g.y, w1.w, fmaf(g.z, w2.w, fmaf(g.w, w3.w, acc[i][3]))));
        }
    }
    float4 b4 = *(const float4*)(bias + tc * 4);
#pragma unroll
    for (int i = 0; i < 8; ++i) {
        int row = m0 + tr * 8 + i;
        ushort4 o;
        o.x = f2bf(acc[i][0] + b4.x); o.y = f2bf(acc[i][1] + b4.y);
        o.z = f2bf(acc[i][2] + b4.z); o.w = f2bf(acc[i][3] + b4.w);
        *(ushort4*)(HB + (size_t)row * DM + tc * 4) = o;
    }
}

// ---------- K5: SB[l][n][128] for both layers ----------
__global__ __launch_bounds__(128) void k_sb(const int* __restrict__ deg,
                                            const float* __restrict__ S,
                                            const float* __restrict__ node_b_all,  // [2][3][128]
                                            const float* __restrict__ edge_W_all,  // [2][2][16][128]
                                            const float* __restrict__ edge_b_all,  // [2][2][128]
                                            float* __restrict__ SBall) {
    int l = blockIdx.x / NNODES, n = blockIdx.x - l * NNODES;
    int j = threadIdx.x;
    const float* node_b = node_b_all + (size_t)l * 3 * DM;
    const float* edge_W = edge_W_all + (size_t)l * 2 * 16 * DM;
    const float* edge_b = edge_b_all + (size_t)l * 2 * DM;
    __shared__ float sS[2][16];
    __shared__ int sdeg[3];
    if (j < 32) sS[j >> 4][j & 15] = S[(((j >> 4)) * NNODES + n) * 16 + (j & 15)];
    if (j >= 32 && j < 35) sdeg[j - 32] = deg[(j - 32) * NNODES + n];
    __syncthreads();
    float val = 0.f;
#pragma unroll
    for (int r = 0; r < 3; ++r) val += (float)sdeg[r] * node_b[r * DM + j];
#pragma unroll
    for (int r = 0; r < 2; ++r) {
        val += (float)sdeg[r] * edge_b[r * DM + j];
#pragma unroll
        for (int k = 0; k < 16; ++k) val += sS[r][k] * edge_W[(r * 16 + k) * DM + j];
    }
    SBall[((size_t)l * NNODES + n) * DM + j] = val;
}

// ---------- K6: SpMM over bf16 HB ----------
// G[b*N+n][r*128+c] = sum_{e: dst=n} HB[b][src(e)][c].  32 lanes x ushort4 per row.
__global__ __launch_bounds__(256) void k_spmm(const unsigned short* __restrict__ HB,
                                              const int* __restrict__ deg,
                                              const int* __restrict__ srcs,
                                              unsigned short* __restrict__ G) {
    int blk = blockIdx.x;                      // 10000
    int b = (blk >> 1) & 3;                    // XCD pair -> batch
    int idx = ((blk >> 3) << 1) + (blk & 1);   // [0, 2500)
    int n = idx * 8 + (threadIdx.x >> 5);
    int lane32 = threadIdx.x & 31;
    int c4 = lane32 * 4;
    const unsigned short* Hb = HB + (size_t)b * NNODES * DM;
    size_t rowbase = ((size_t)(b * NNODES + n)) * 384;
#pragma unroll
    for (int r = 0; r < 3; ++r) {
        int dg = deg[r * NNODES + n];
        const int* bk = srcs + (size_t)(r * NNODES + n) * CAP;
        float a0 = 0.f, a1 = 0.f, a2 = 0.f, a3 = 0.f;
        int j = 0;
        for (; j + 3 < dg; j += 4) {
            int4 sidx = *(const int4*)&bk[j];
            ushort4 v0 = *(const ushort4*)(Hb + (size_t)sidx.x * DM + c4);
            ushort4 v1 = *(const ushort4*)(Hb + (size_t)sidx.y * DM + c4);
            ushort4 v2 = *(const ushort4*)(Hb + (size_t)sidx.z * DM + c4);
            ushort4 v3 = *(const ushort4*)(Hb + (size_t)sidx.w * DM + c4);
            a0 += bf2f(v0.x) + bf2f(v1.x) + bf2f(v2.x) + bf2f(v3.x);
            a1 += bf2f(v0.y) + bf2f(v1.y) + bf2f(v2.y) + bf2f(v3.y);
            a2 += bf2f(v0.z) + bf2f(v1.z) + bf2f(v2.z) + bf2f(v3.z);
            a3 += bf2f(v0.w) + bf2f(v1.w) + bf2f(v2.w) + bf2f(v3.w);
        }
        for (; j < dg; ++j) {
            int s0 = bk[j];
            ushort4 v0 = *(const ushort4*)(Hb + (size_t)s0 * DM + c4);
            a0 += bf2f(v0.x); a1 += bf2f(v0.y); a2 += bf2f(v0.z); a3 += bf2f(v0.w);
        }
        ushort4 hv;
        hv.x = f2bf(a0); hv.y = f2bf(a1); hv.z = f2bf(a2); hv.w = f2bf(a3);
        *(ushort4*)(G + rowbase + r * 128 + c4) = hv;
    }
}

// ---------- K7: bf16 MFMA GEMM [64x384]@[384x128] + bias + residual + ReLU + LN ----------
// A-frag: A[m=lane&15][k=(lane>>4)*8+j]; C/D: col=lane&15, row=(lane>>4)*4+reg.
// Residual read from HB (bf16); writes HB in place (layer 0) or fp32 out (layer 1).
__global__ __launch_bounds__(256) void k_gemm_ln(const unsigned short* __restrict__ G,   // [BROWS][384] bf16
                                                 const unsigned short* __restrict__ Wt,  // [128 n][384 k] bf16
                                                 const float* __restrict__ SB,
                                                 unsigned short* HB,
                                                 const float* __restrict__ lng,
                                                 const float* __restrict__ lnb,
                                                 float* out, int write_f32) {
    __shared__ __align__(16) unsigned short Gs[64][104];
    __shared__ __align__(16) unsigned short Ws[128][104];
    int t = threadIdx.x;
    int m0 = blockIdx.x * 64;
    int w = t >> 6, lane = t & 63;
    int q = lane >> 4, lm = lane & 15;

    f32x4 acc[8];
#pragma unroll
    for (int ct = 0; ct < 8; ++ct) acc[ct] = (f32x4){0.f, 0.f, 0.f, 0.f};

    for (int kc = 0; kc < 4; ++kc) {
#pragma unroll
        for (int i = 0; i < 3; ++i) {
            int lin = t + 256 * i;
            int row = lin / 12, seg = lin % 12;
            *(uint4*)&Gs[row][seg * 8] =
                *(const uint4*)(G + (size_t)(m0 + row) * 384 + kc * 96 + seg * 8);
        }
#pragma unroll
        for (int i = 0; i < 6; ++i) {
            int lin = t + 256 * i;
            int row = lin / 12, seg = lin % 12;
            *(uint4*)&Ws[row][seg * 8] =
                *(const uint4*)(Wt + (size_t)row * 384 + kc * 96 + seg * 8);
        }
        __syncthreads();
#pragma unroll
        for (int kt = 0; kt < 3; ++kt) {
            bf16x8 a = *(const bf16x8*)&Gs[w * 16 + lm][kt * 32 + q * 8];
#pragma unroll
            for (int ct = 0; ct < 8; ++ct) {
                bf16x8 bf = *(const bf16x8*)&Ws[ct * 16 + lm][kt * 32 + q * 8];
                acc[ct] = __builtin_amdgcn_mfma_f32_16x16x32_bf16(a, bf, acc[ct], 0, 0, 0);
            }
        }
        __syncthreads();
    }

    float gc[8], bc[8];
#pragma unroll
    for (int ct = 0; ct < 8; ++ct) {
        int col = ct * 16 + lm;
        gc[ct] = lng[col]; bc[ct] = lnb[col];
    }
#pragma unroll
    for (int reg = 0; reg < 4; ++reg) {
        int row = m0 + w * 16 + q * 4 + reg;
        int n = row % NNODES;
        float xv[8];
        float s1 = 0.f, s2 = 0.f;
#pragma unroll
        for (int ct = 0; ct < 8; ++ct) {
            int col = ct * 16 + lm;
            float h  = bf2f(HB[(size_t)row * DM + col]);
            float sb = SB[(size_t)n * DM + col];
            float v = h + fmaxf(acc[ct][reg] + sb, 0.f);
            xv[ct] = v; s1 += v; s2 += v * v;
        }
#pragma unroll
        for (int m = 1; m <= 8; m <<= 1) {
            s1 += __shfl_xor(s1, m, 64);
            s2 += __shfl_xor(s2, m, 64);
        }
        float mu  = s1 * (1.f / 128.f);
        float var = s2 * (1.f / 128.f) - mu * mu;
        float inv = rsqrtf(var + LN_EPS);
        if (write_f32) {
#pragma unroll
            for (int ct = 0; ct < 8; ++ct) {
                int col = ct * 16 + lm;
                out[(size_t)row * DM + col] = (xv[ct] - mu) * inv * gc[ct] + bc[ct];
            }
        } else {
#pragma unroll
            for (int ct = 0; ct < 8; ++ct) {
                int col = ct * 16 + lm;
                HB[(size_t)row * DM + col] = f2bf((xv[ct] - mu) * inv * gc[ct] + bc[ct]);
            }
        }
    }
}

extern "C" void kernel_launch(void* const* d_in, const int* in_sizes, int n_in,
                              void* d_out, int out_size, void* d_ws, size_t ws_size,
                              hipStream_t stream) {
    const float* node_feat = (const float*)d_in[0];
    const float* in_W   = (const float*)d_in[1];
    const float* in_b   = (const float*)d_in[2];
    const float* node_W = (const float*)d_in[3];   // [2][3][128][128]
    const float* node_b = (const float*)d_in[4];   // [2][3][128]
    const float* edge_W = (const float*)d_in[5];   // [2][2][16][128]
    const float* edge_b = (const float*)d_in[6];   // [2][2][128]
    const float* ln_g   = (const float*)d_in[7];   // [2][128]
    const float* ln_b   = (const float*)d_in[8];   // [2][128]
    const float* ea0    = (const float*)d_in[9];
    const float* ea1    = (const float*)d_in[10];
    const int*   ei0    = (const int*)d_in[11];
    const int*   ei1    = (const int*)d_in[12];
    const int*   ei2    = (const int*)d_in[13];
    float* out = (float*)d_out;

    char* ws = (char*)d_ws;
    size_t off = 0;
    auto alloc = [&](size_t bytes) -> void* {
        void* p = ws + off;
        off = (off + bytes + 255) & ~(size_t)255;
        return p;
    };
    unsigned short* HB     = (unsigned short*)alloc((size_t)BROWS * DM * 2);       // 20.5 MB
    unsigned short* G      = (unsigned short*)alloc((size_t)BROWS * 384 * 2);      // 61 MB
    float*          SB     = (float*)alloc((size_t)2 * NNODES * DM * 4);           // 20.5 MB
    int*            cursor = (int*)alloc((size_t)3 * NNODES * 4);                  // zeroed
    float*          S      = (float*)alloc((size_t)2 * NNODES * 16 * 4);           // zeroed
    int*            srcs   = (int*)alloc((size_t)3 * NNODES * CAP * 4);            // 15 MB
    unsigned short* Wt     = (unsigned short*)alloc((size_t)2 * 128 * 384 * 2);

    // cursor and S are adjacent (modulo 256-pad) -> one memset covering both
    hipMemsetAsync(cursor, 0, (size_t)((char*)srcs - (char*)cursor), stream);

    k_scatter<<<(3 * NE + 255) / 256, 256, 0, stream>>>(ei0, ei1, ei2, cursor, srcs);
    k_ea<<<(2 * NE * 4 + 255) / 256, 256, 0, stream>>>(ei0, ei1, ea0, ea1, S);
    k_wprep<<<384, 256, 0, stream>>>(node_W, Wt);
    k_proj<<<BROWS / 64, 256, 0, stream>>>(node_feat, in_W, in_b, HB);
    k_sb<<<2 * NNODES, 128, 0, stream>>>(cursor, S, node_b, edge_W, edge_b, SB);

    for (int l = 0; l < 2; ++l) {
        k_spmm<<<10000, 256, 0, stream>>>(HB, cursor, srcs, G);
        k_gemm_ln<<<BROWS / 64, 256, 0, stream>>>(G, Wt + (size_t)l * 128 * 384,
                                                  SB + (size_t)l * NNODES * DM, HB,
                                                  ln_g + (size_t)l * DM, ln_b + (size_t)l * DM,
                                                  out, l == 1);
    }
}